// Round 3
// baseline (147.503 us; speedup 1.0000x reference)
//
#include <hip/hip_runtime.h>

typedef __attribute__((ext_vector_type(8))) short short8;
typedef __attribute__((ext_vector_type(4))) float f32x4;
typedef unsigned short u16;
typedef unsigned int u32;

#define NNODES 65536
#define FDIM 128

__device__ __forceinline__ u16 f2bf(float f) {
    u32 u = __float_as_uint(f);
    u32 r = (u + 0x7fffu + ((u >> 16) & 1u)) >> 16;   // RNE
    return (u16)r;
}
__device__ __forceinline__ u32 pack2bf(float lo, float hi) {
    return ((u32)f2bf(hi) << 16) | f2bf(lo);
}

// ---------- rowptr via binary search over sorted edge_row ----------
__global__ void rowptr_kernel(const int* __restrict__ erow, int* __restrict__ rowptr,
                              int n, int e) {
    int r = blockIdx.x * blockDim.x + threadIdx.x;
    if (r > n) return;
    int lo = 0, hi = e;
    while (lo < hi) {
        int mid = (lo + hi) >> 1;
        if (erow[mid] < r) lo = mid + 1; else hi = mid;
    }
    rowptr[r] = lo;
}

// ---------- x fp32 -> bf16 ----------
__global__ void cvt_x_kernel(const float* __restrict__ x, u16* __restrict__ xb, int total4) {
    int i = blockIdx.x * blockDim.x + threadIdx.x;
    if (i >= total4) return;
    float4 v = reinterpret_cast<const float4*>(x)[i];
    uint2 p;
    p.x = pack2bf(v.x, v.y);
    p.y = pack2bf(v.z, v.w);
    reinterpret_cast<uint2*>(xb)[i] = p;
}

// ---------- weight fp32 [K][NC] -> bf16 transposed [NC][K] ----------
__global__ void cvt_wT_kernel(const float* __restrict__ w, u16* __restrict__ wt,
                              int K, int NC) {
    int idx = blockIdx.x * blockDim.x + threadIdx.x;
    if (idx >= K * NC) return;
    int n = idx / K, k = idx - n * K;
    wt[idx] = f2bf(w[k * NC + n]);
}

// ---------- SpMM: one wave per row, 4 edges in flight ----------
__global__ void spmm_kernel(const u16* __restrict__ h, const int* __restrict__ rowptr,
                            const int* __restrict__ col, const float* __restrict__ val,
                            u16* __restrict__ y, int n) {
    int wid = (blockIdx.x * blockDim.x + threadIdx.x) >> 6;
    int lane = threadIdx.x & 63;
    if (wid >= n) return;
    const int slot = lane >> 4;
    const int fg = lane & 15;
    int s = rowptr[wid], e = rowptr[wid + 1];

    float acc[8];
#pragma unroll
    for (int j = 0; j < 8; ++j) acc[j] = 0.f;

    int i = s + slot;
    int c = 0; float v = 0.f;
    if (i < e) { c = col[i]; v = val[i]; }
    while (i < e) {
        int inext = i + 4;
        int cn = 0; float vn = 0.f;
        if (inext < e) { cn = col[inext]; vn = val[inext]; }   // prefetch next chunk
        short8 hv = *reinterpret_cast<const short8*>(h + (size_t)c * FDIM + fg * 8);
#pragma unroll
        for (int j = 0; j < 8; ++j) {
            float f = __uint_as_float(((u32)(u16)hv[j]) << 16);
            acc[j] = fmaf(v, f, acc[j]);
        }
        i = inext; c = cn; v = vn;
    }

#pragma unroll
    for (int m = 16; m <= 32; m <<= 1)
#pragma unroll
        for (int j = 0; j < 8; ++j)
            acc[j] += __shfl_xor(acc[j], m, 64);

    float a0 = 0.f, a1 = 0.f;
#pragma unroll
    for (int ss = 0; ss < 4; ++ss)
        if (slot == ss) { a0 = acc[ss * 2]; a1 = acc[ss * 2 + 1]; }
    *reinterpret_cast<u32*>(y + (size_t)wid * FDIM + fg * 8 + slot * 2) = pack2bf(a0, a1);
}

// ---------- GEMM v2: out[M][NT*16] = A[M][128] @ W (WT passed as [NC][K]) ----------
// Swapped-operand MFMA: D = mfma(Wfrag, Yfrag) so lane (dn=lane&15, kg=lane>>4)
// holds out[node row r0+dn][cols nt*16 + kg*4 + 0..3] -> contiguous 8B (bf16) /
// 16B (fp32) packed stores. Mapping from verified C/D layout (col=lane&15 -> N
// operand = node row; row=kg*4+reg -> M operand = weight col).
template<int NT, bool RELU, bool OUT_BF16>
__global__ void gemm_kernel(const u16* __restrict__ A, const u16* __restrict__ WT,
                            void* __restrict__ out, int M) {
    const int lane = threadIdx.x & 63;
    const int dn = lane & 15;
    const int kg = lane >> 4;

    short8 bf[NT][4];   // first operand: m = wcol = nt*16+dn, k = s*32 + kg*8
#pragma unroll
    for (int nt = 0; nt < NT; ++nt)
#pragma unroll
        for (int s = 0; s < 4; ++s)
            bf[nt][s] = *reinterpret_cast<const short8*>(
                &WT[(size_t)(nt * 16 + dn) * 128 + s * 32 + kg * 8]);

    const int nwaves = (gridDim.x * blockDim.x) >> 6;
    const int gwave  = (blockIdx.x * blockDim.x + threadIdx.x) >> 6;
    const int nchunk = M >> 4;

    for (int ch = gwave; ch < nchunk; ch += nwaves) {
        const int r0 = ch << 4;
        f32x4 acc[NT];
#pragma unroll
        for (int nt = 0; nt < NT; ++nt) acc[nt] = (f32x4){0.f, 0.f, 0.f, 0.f};

#pragma unroll
        for (int s = 0; s < 4; ++s) {
            short8 a = *reinterpret_cast<const short8*>(
                &A[(size_t)(r0 + dn) * 128 + s * 32 + kg * 8]);
#pragma unroll
            for (int nt = 0; nt < NT; ++nt)
                acc[nt] = __builtin_amdgcn_mfma_f32_16x16x32_bf16(bf[nt][s], a, acc[nt], 0, 0, 0);
        }

        const int row = r0 + dn;
#pragma unroll
        for (int nt = 0; nt < NT; ++nt) {
            float v0 = acc[nt][0], v1 = acc[nt][1], v2 = acc[nt][2], v3 = acc[nt][3];
            if (RELU) {
                v0 = fmaxf(v0, 0.f); v1 = fmaxf(v1, 0.f);
                v2 = fmaxf(v2, 0.f); v3 = fmaxf(v3, 0.f);
            }
            if (OUT_BF16) {
                uint2 p; p.x = pack2bf(v0, v1); p.y = pack2bf(v2, v3);
                *reinterpret_cast<uint2*>(
                    (u16*)out + (size_t)row * (NT * 16) + nt * 16 + kg * 4) = p;
            } else {
                float4 p = make_float4(v0, v1, v2, v3);
                *reinterpret_cast<float4*>(
                    (float*)out + (size_t)row * (NT * 16) + nt * 16 + kg * 4) = p;
            }
        }
    }
}

extern "C" void kernel_launch(void* const* d_in, const int* in_sizes, int n_in,
                              void* d_out, int out_size, void* d_ws, size_t ws_size,
                              hipStream_t stream) {
    const float* x    = (const float*)d_in[0];
    const float* w1   = (const float*)d_in[1];
    const float* w2   = (const float*)d_in[2];
    const float* w3   = (const float*)d_in[3];
    const int*   erow = (const int*)d_in[4];
    const int*   ecol = (const int*)d_in[5];
    const float* eval = (const float*)d_in[6];
    float* out = (float*)d_out;

    const int N = in_sizes[0] / FDIM;
    const int E = in_sizes[4];

    char* ws = (char*)d_ws;
    int* rowptr = (int*)ws;                                  // (N+1)*4
    u16* wt1 = (u16*)(ws + (512 << 10));                     // 32KB
    u16* wt2 = wt1 + 128 * 128;                              // 32KB
    u16* wt3 = wt2 + 128 * 128;                              // 16KB
    u16* ybuf = (u16*)(ws + (1 << 20));                      // 16MB bf16 [N][128]
    u16* hbuf = (u16*)(ws + (18u << 20));                    // 16MB bf16 [N][128]

    rowptr_kernel<<<(N + 1 + 255) / 256, 256, 0, stream>>>(erow, rowptr, N, E);
    cvt_wT_kernel<<<(128 * 128 + 255) / 256, 256, 0, stream>>>(w1, wt1, 128, 128);
    cvt_wT_kernel<<<(128 * 128 + 255) / 256, 256, 0, stream>>>(w2, wt2, 128, 128);
    cvt_wT_kernel<<<(64 * 128 + 255) / 256, 256, 0, stream>>>(w3, wt3, 128, 64);
    cvt_x_kernel<<<(N * FDIM / 4 + 255) / 256, 256, 0, stream>>>(x, hbuf, N * FDIM / 4);
    spmm_kernel<<<N / 4, 256, 0, stream>>>(hbuf, rowptr, ecol, eval, ybuf, N);
    gemm_kernel<8, true, true><<<512, 256, 0, stream>>>(ybuf, wt1, hbuf, N);
    spmm_kernel<<<N / 4, 256, 0, stream>>>(hbuf, rowptr, ecol, eval, ybuf, N);
    gemm_kernel<8, true, true><<<512, 256, 0, stream>>>(ybuf, wt2, hbuf, N);
    gemm_kernel<4, false, false><<<1024, 256, 0, stream>>>(hbuf, wt3, (void*)out, N);
}

// Round 4
// 117.397 us; speedup vs baseline: 1.2564x; 1.2564x over previous
//
#include <hip/hip_runtime.h>

typedef __attribute__((ext_vector_type(8))) short short8;
typedef __attribute__((ext_vector_type(4))) float f32x4;
typedef unsigned short u16;
typedef unsigned int u32;

#define NNODES 65536
#define FDIM 128

__device__ __forceinline__ u16 f2bf(float f) {
    u32 u = __float_as_uint(f);
    u32 r = (u + 0x7fffu + ((u >> 16) & 1u)) >> 16;   // RNE
    return (u16)r;
}
__device__ __forceinline__ u32 pack2bf(float lo, float hi) {
    return ((u32)f2bf(hi) << 16) | f2bf(lo);
}

// ---------- rowptr via binary search over sorted edge_row ----------
__global__ void rowptr_kernel(const int* __restrict__ erow, int* __restrict__ rowptr,
                              int n, int e) {
    int r = blockIdx.x * blockDim.x + threadIdx.x;
    if (r > n) return;
    int lo = 0, hi = e;
    while (lo < hi) {
        int mid = (lo + hi) >> 1;
        if (erow[mid] < r) lo = mid + 1; else hi = mid;
    }
    rowptr[r] = lo;
}

// ---------- x fp32 -> bf16 ----------
__global__ void cvt_x_kernel(const float* __restrict__ x, u16* __restrict__ xb, int total4) {
    int i = blockIdx.x * blockDim.x + threadIdx.x;
    if (i >= total4) return;
    float4 v = reinterpret_cast<const float4*>(x)[i];
    uint2 p;
    p.x = pack2bf(v.x, v.y);
    p.y = pack2bf(v.z, v.w);
    reinterpret_cast<uint2*>(xb)[i] = p;
}

// ---------- weight fp32 [K][NC] -> bf16 transposed [NC][K] ----------
__global__ void cvt_wT_kernel(const float* __restrict__ w, u16* __restrict__ wt,
                              int K, int NC) {
    int idx = blockIdx.x * blockDim.x + threadIdx.x;
    if (idx >= K * NC) return;
    int n = idx / K, k = idx - n * K;
    wt[idx] = f2bf(w[k * NC + n]);
}

// ---------- SpMM: one wave per row, 4 edges in flight ----------
__global__ void spmm_kernel(const u16* __restrict__ h, const int* __restrict__ rowptr,
                            const int* __restrict__ col, const float* __restrict__ val,
                            u16* __restrict__ y, int n) {
    int wid = (blockIdx.x * blockDim.x + threadIdx.x) >> 6;
    int lane = threadIdx.x & 63;
    if (wid >= n) return;
    const int slot = lane >> 4;
    const int fg = lane & 15;
    int s = rowptr[wid], e = rowptr[wid + 1];

    float acc[8];
#pragma unroll
    for (int j = 0; j < 8; ++j) acc[j] = 0.f;

    int i = s + slot;
    int c = 0; float v = 0.f;
    if (i < e) { c = col[i]; v = val[i]; }
    while (i < e) {
        int inext = i + 4;
        int cn = 0; float vn = 0.f;
        if (inext < e) { cn = col[inext]; vn = val[inext]; }   // prefetch next chunk
        short8 hv = *reinterpret_cast<const short8*>(h + (size_t)c * FDIM + fg * 8);
#pragma unroll
        for (int j = 0; j < 8; ++j) {
            float f = __uint_as_float(((u32)(u16)hv[j]) << 16);
            acc[j] = fmaf(v, f, acc[j]);
        }
        i = inext; c = cn; v = vn;
    }

#pragma unroll
    for (int m = 16; m <= 32; m <<= 1)
#pragma unroll
        for (int j = 0; j < 8; ++j)
            acc[j] += __shfl_xor(acc[j], m, 64);

    float a0 = 0.f, a1 = 0.f;
#pragma unroll
    for (int ss = 0; ss < 4; ++ss)
        if (slot == ss) { a0 = acc[ss * 2]; a1 = acc[ss * 2 + 1]; }
    *reinterpret_cast<u32*>(y + (size_t)wid * FDIM + fg * 8 + slot * 2) = pack2bf(a0, a1);
}

// ---------- GEMM v3: LDS-staged weights, one 16-row chunk per wave ----------
// WT [NC][128] bf16 staged into LDS with padded stride 136 u16 (272B) so the
// fragment ds_read_b128 (bank = 4*(dn+kg) mod 32) spreads over 8 bank-slots:
// conflict-free floor. Live VGPRs ~50: no spill (R3's 50us was scratch spill
// of 128 reg-resident weight frags at a compiler-chosen 64-VGPR budget).
// Swapped-operand MFMA: D=mfma(Wfrag, Afrag) -> lane (dn,kg) holds
// out[r0+dn][nt*16+kg*4+0..3] -> contiguous 8B/16B stores.
template<int NT, bool RELU, bool OUT_BF16>
__global__ __launch_bounds__(256, 4)
void gemm_kernel(const u16* __restrict__ A, const u16* __restrict__ WT,
                 void* __restrict__ out, int M) {
    constexpr int NC = NT * 16;
    constexpr int LSTR = 136;                 // u16: 128 data + 8 pad
    __shared__ u16 wlds[NC * LSTR];

    const int t = threadIdx.x;
    const int fr = t & 15;                    // 16B chunk within a 256B row
#pragma unroll
    for (int n = t >> 4; n < NC; n += 16)
        *reinterpret_cast<uint4*>(&wlds[n * LSTR + fr * 8]) =
            *reinterpret_cast<const uint4*>(&WT[(size_t)n * 128 + fr * 8]);
    __syncthreads();

    const int lane = t & 63;
    const int dn = lane & 15;
    const int kg = lane >> 4;
    const int r0 = (blockIdx.x * 4 + (t >> 6)) << 4;
    if (r0 >= M) return;

    f32x4 acc[NT];
#pragma unroll
    for (int nt = 0; nt < NT; ++nt) acc[nt] = (f32x4){0.f, 0.f, 0.f, 0.f};

#pragma unroll
    for (int s = 0; s < 4; ++s) {
        short8 a = *reinterpret_cast<const short8*>(
            &A[(size_t)(r0 + dn) * 128 + s * 32 + kg * 8]);
#pragma unroll
        for (int nt = 0; nt < NT; ++nt) {
            short8 b = *reinterpret_cast<const short8*>(
                &wlds[(nt * 16 + dn) * LSTR + s * 32 + kg * 8]);
            acc[nt] = __builtin_amdgcn_mfma_f32_16x16x32_bf16(b, a, acc[nt], 0, 0, 0);
        }
    }

    const int row = r0 + dn;
#pragma unroll
    for (int nt = 0; nt < NT; ++nt) {
        float v0 = acc[nt][0], v1 = acc[nt][1], v2 = acc[nt][2], v3 = acc[nt][3];
        if (RELU) {
            v0 = fmaxf(v0, 0.f); v1 = fmaxf(v1, 0.f);
            v2 = fmaxf(v2, 0.f); v3 = fmaxf(v3, 0.f);
        }
        if (OUT_BF16) {
            uint2 p; p.x = pack2bf(v0, v1); p.y = pack2bf(v2, v3);
            *reinterpret_cast<uint2*>(
                (u16*)out + (size_t)row * NC + nt * 16 + kg * 4) = p;
        } else {
            float4 p = make_float4(v0, v1, v2, v3);
            *reinterpret_cast<float4*>(
                (float*)out + (size_t)row * NC + nt * 16 + kg * 4) = p;
        }
    }
}

extern "C" void kernel_launch(void* const* d_in, const int* in_sizes, int n_in,
                              void* d_out, int out_size, void* d_ws, size_t ws_size,
                              hipStream_t stream) {
    const float* x    = (const float*)d_in[0];
    const float* w1   = (const float*)d_in[1];
    const float* w2   = (const float*)d_in[2];
    const float* w3   = (const float*)d_in[3];
    const int*   erow = (const int*)d_in[4];
    const int*   ecol = (const int*)d_in[5];
    const float* eval = (const float*)d_in[6];
    float* out = (float*)d_out;

    const int N = in_sizes[0] / FDIM;
    const int E = in_sizes[4];

    char* ws = (char*)d_ws;
    int* rowptr = (int*)ws;                                  // (N+1)*4
    u16* wt1 = (u16*)(ws + (512 << 10));                     // 32KB
    u16* wt2 = wt1 + 128 * 128;                              // 32KB
    u16* wt3 = wt2 + 128 * 128;                              // 16KB
    u16* ybuf = (u16*)(ws + (1 << 20));                      // 16MB bf16 [N][128]
    u16* hbuf = (u16*)(ws + (18u << 20));                    // 16MB bf16 [N][128]

    rowptr_kernel<<<(N + 1 + 255) / 256, 256, 0, stream>>>(erow, rowptr, N, E);
    cvt_wT_kernel<<<(128 * 128 + 255) / 256, 256, 0, stream>>>(w1, wt1, 128, 128);
    cvt_wT_kernel<<<(128 * 128 + 255) / 256, 256, 0, stream>>>(w2, wt2, 128, 128);
    cvt_wT_kernel<<<(64 * 128 + 255) / 256, 256, 0, stream>>>(w3, wt3, 128, 64);
    cvt_x_kernel<<<(N * FDIM / 4 + 255) / 256, 256, 0, stream>>>(x, hbuf, N * FDIM / 4);
    spmm_kernel<<<N / 4, 256, 0, stream>>>(hbuf, rowptr, ecol, eval, ybuf, N);
    gemm_kernel<8, true, true><<<N / 64, 256, 0, stream>>>(ybuf, wt1, hbuf, N);
    spmm_kernel<<<N / 4, 256, 0, stream>>>(hbuf, rowptr, ecol, eval, ybuf, N);
    gemm_kernel<8, true, true><<<N / 64, 256, 0, stream>>>(ybuf, wt2, hbuf, N);
    gemm_kernel<4, false, false><<<N / 64, 256, 0, stream>>>(hbuf, wt3, (void*)out, N);
}